// Round 1
// baseline (195.223 us; speedup 1.0000x reference)
//
#include <hip/hip_runtime.h>
#include <math.h>

#define A_N 2048
#define H_N 256
#define NLAYERS 2057

// ws layout (float offsets)
#define PART_OFF  0               // 2049*256 = 524544
#define PART2_OFF 524544          // 64*256 = 16384
#define UMID_OFF  540928          // 256
#define GSUM_OFF  541184
#define WSUM_OFF  541185

// ---- helpers (single 256-thread block) ----

// softmax-2 head: dest[0..1] = softmax(sx @ W2 + b2) * scale
__device__ __forceinline__ void head256(const float* sx, float* r0, float* r1,
                                        const float* W2, const float* b2,
                                        float scale, float* dest, int t)
{
    float xv = sx[t];
    r0[t] = xv * W2[2*t];
    r1[t] = xv * W2[2*t+1];
    __syncthreads();
    for (int s = 128; s > 0; s >>= 1) {
        if (t < s) { r0[t] += r0[t+s]; r1[t] += r1[t+s]; }
        __syncthreads();
    }
    if (t == 0) {
        float o0 = r0[0] + b2[0], o1 = r1[0] + b2[1];
        float m  = fmaxf(o0, o1);
        float e0 = expf(o0 - m), e1 = expf(o1 - m);
        float inv = scale / (e0 + e1);
        dest[0] = e0 * inv;
        dest[1] = e1 * inv;
    }
    __syncthreads();
}

// sx = relu(sx @ W + b), W is [256][256] row-major
__device__ __forceinline__ void mv256(float* sx, const float* __restrict__ W,
                                      const float* __restrict__ b, int t)
{
    float acc = 0.f;
    #pragma unroll 8
    for (int k = 0; k < 256; ++k) acc += sx[k] * W[k*256 + t];
    acc = fmaxf(acc + b[t], 0.f);
    __syncthreads();
    sx[t] = acc;
    __syncthreads();
}

// ---- kernel 1: sums + base stack + middle (1 block) ----
__global__ __launch_bounds__(256) void k_base(
    const int* __restrict__ Xm, const float* __restrict__ bfv,
    const float* __restrict__ Wbf, const float* __restrict__ bbf,
    const float* __restrict__ Wbr, const float* __restrict__ bbr,
    const float* __restrict__ Wbo, const float* __restrict__ bbo,
    const float* __restrict__ Wm, const float* __restrict__ bm,
    const float* __restrict__ Wmo, const float* __restrict__ bmo,
    const float* __restrict__ lw, float* __restrict__ out,
    float* __restrict__ ws)
{
    __shared__ float sx[256], r0[256], r1[256];
    int t = threadIdx.x;

    // mask-weighted sums
    float ga = 0.f;
    for (int a = t; a < A_N; a += 256) if (Xm[a] != 0) ga += lw[4 + a];
    r0[t] = ga; __syncthreads();
    for (int s = 128; s > 0; s >>= 1) { if (t < s) r0[t] += r0[t+s]; __syncthreads(); }
    if (t == 0) {
        float gaux = r0[0];
        ws[GSUM_OFF] = gaux + lw[2056];
        ws[WSUM_OFF] = lw[0]+lw[1]+lw[2]+lw[3] + gaux
                     + lw[2052]+lw[2053]+lw[2054]+lw[2055]+lw[2056];
    }
    __syncthreads();

    // base stack
    sx[t] = fmaxf(bfv[0] * Wbf[t] + bbf[t], 0.f);
    __syncthreads();
    head256(sx, r0, r1, Wbo, bbo, lw[0], out + 2, t);
    for (int i = 0; i < 3; ++i) {
        mv256(sx, Wbr + i*65536, bbr + i*256, t);
        head256(sx, r0, r1, Wbo + (i+1)*512, bbo + (i+1)*2, lw[i+1],
                out + 2 + (i+1)*2, t);
    }
    // middle
    mv256(sx, Wm, bm, t);
    ws[UMID_OFF + t] = sx[t] * lw[2056];     // unscaled-by-gsum end_input tail
    head256(sx, r0, r1, Wmo, bmo, lw[2056], out + 2 + 2056*2, t);
}

// ---- kernel 2: aux experts + partial big matvec (2049 blocks) ----
__global__ __launch_bounds__(256) void k_big(
    const float* __restrict__ X, const int* __restrict__ Xm,
    const float* __restrict__ Wa, const float* __restrict__ ba,
    const float* __restrict__ Wao, const float* __restrict__ bao,
    const float* __restrict__ Wef, const float* __restrict__ lw,
    float* __restrict__ out, float* __restrict__ ws)
{
    __shared__ float sg[256];
    __shared__ float sacc[4][256];
    int b = blockIdx.x, t = threadIdx.x;
    float* part = ws + PART_OFF;

    if (b < A_N) {
        if (Xm[b] == 0) {                      // masked expert: zero row, skip 256KB
            part[b*256 + t] = 0.f;
            if (t == 0) { out[2 + (4+b)*2] = 0.f; out[2 + (4+b)*2 + 1] = 0.f; }
            return;
        }
        float xv = X[b];
        float w  = lw[4 + b];
        float h  = fmaxf(xv * Wa[b*256 + t] + ba[b*256 + t], 0.f);
        float2 wo = *(const float2*)&Wao[(size_t)b*512 + 2*t];
        sacc[0][t] = h * wo.x;
        sacc[1][t] = h * wo.y;
        sg[t] = h * w;                         // u = h*mask*lw (mask==1 here)
        __syncthreads();
        for (int s = 128; s > 0; s >>= 1) {
            if (t < s) { sacc[0][t] += sacc[0][t+s]; sacc[1][t] += sacc[1][t+s]; }
            __syncthreads();
        }
        if (t == 0) {
            float o0 = sacc[0][0] + bao[2*b], o1 = sacc[1][0] + bao[2*b+1];
            float m  = fmaxf(o0, o1);
            float e0 = expf(o0 - m), e1 = expf(o1 - m);
            float inv = w / (e0 + e1);         // * lw * mask, /wsum deferred
            out[2 + (4+b)*2]     = e0 * inv;
            out[2 + (4+b)*2 + 1] = e1 * inv;
        }
        __syncthreads();
    } else {                                   // middle chunk
        sg[t] = ws[UMID_OFF + t];
        __syncthreads();
    }

    // partial matvec: rows [b*256, b*256+256) of We_first
    int quad = t >> 6, lane = t & 63;
    const float4* Wrow = (const float4*)(Wef + (size_t)b * 65536);
    float4 acc = {0.f, 0.f, 0.f, 0.f};
    #pragma unroll 4
    for (int it = 0; it < 64; ++it) {
        int r = it*4 + quad;
        float gv = sg[r];
        float4 wv = Wrow[(size_t)r*64 + lane];
        acc.x += gv*wv.x; acc.y += gv*wv.y; acc.z += gv*wv.z; acc.w += gv*wv.w;
    }
    sacc[quad][lane*4 + 0] = acc.x;
    sacc[quad][lane*4 + 1] = acc.y;
    sacc[quad][lane*4 + 2] = acc.z;
    sacc[quad][lane*4 + 3] = acc.w;
    __syncthreads();
    part[b*256 + t] = sacc[0][t] + sacc[1][t] + sacc[2][t] + sacc[3][t];
}

// ---- kernel 3: reduce part[2049][256] -> part2[64][256] ----
__global__ __launch_bounds__(256) void k_red(float* __restrict__ ws)
{
    int r = blockIdx.x, t = threadIdx.x;
    float acc = 0.f;
    for (int b = r; b < A_N + 1; b += 64) acc += ws[PART_OFF + b*256 + t];
    ws[PART2_OFF + r*256 + t] = acc;
}

// ---- kernel 4: end stack + final combine (1 block) ----
__global__ __launch_bounds__(256) void k_end(
    const float* __restrict__ bef, const float* __restrict__ Wer,
    const float* __restrict__ ber, const float* __restrict__ Weo,
    const float* __restrict__ beo, const float* __restrict__ lw,
    float* __restrict__ out, float* __restrict__ ws)
{
    __shared__ float sx[256], r0[256], r1[256];
    __shared__ float endraw[4][2];
    int t = threadIdx.x;

    float acc = 0.f;
    for (int r = 0; r < 64; ++r) acc += ws[PART2_OFF + r*256 + t];
    float gsum = ws[GSUM_OFF];
    sx[t] = fmaxf(acc / gsum + bef[t], 0.f);
    __syncthreads();

    head256(sx, r0, r1, Weo, beo, lw[2052], &endraw[0][0], t);
    for (int i = 0; i < 3; ++i) {
        mv256(sx, Wer + i*65536, ber + i*256, t);
        head256(sx, r0, r1, Weo + (i+1)*512, beo + (i+1)*2, lw[2053+i],
                &endraw[i+1][0], t);
    }

    // rescale all rows by 1/wsum, accumulate final logit
    float invw = 1.f / ws[WSUM_OFF];
    float s0 = 0.f, s1 = 0.f;
    for (int i = t; i < NLAYERS; i += 256) {
        float v0, v1;
        if (i >= 2052 && i < 2056) { v0 = endraw[i-2052][0]; v1 = endraw[i-2052][1]; }
        else                        { v0 = out[2 + 2*i];      v1 = out[2 + 2*i + 1]; }
        v0 *= invw; v1 *= invw;
        out[2 + 2*i]     = v0;
        out[2 + 2*i + 1] = v1;
        s0 += v0; s1 += v1;
    }
    r0[t] = s0; r1[t] = s1; __syncthreads();
    for (int s = 128; s > 0; s >>= 1) {
        if (t < s) { r0[t] += r0[t+s]; r1[t] += r1[t+s]; }
        __syncthreads();
    }
    if (t == 0) { out[0] = r0[0]; out[1] = r1[0]; }
}

extern "C" void kernel_launch(void* const* d_in, const int* in_sizes, int n_in,
                              void* d_out, int out_size, void* d_ws, size_t ws_size,
                              hipStream_t stream)
{
    const float* X    = (const float*)d_in[0];
    const int*   Xm   = (const int*)  d_in[1];
    const float* bfv  = (const float*)d_in[2];
    const float* Wbf  = (const float*)d_in[3];
    const float* bbf  = (const float*)d_in[4];
    const float* Wbr  = (const float*)d_in[5];
    const float* bbr  = (const float*)d_in[6];
    const float* Wbo  = (const float*)d_in[7];
    const float* bbo  = (const float*)d_in[8];
    const float* Wm   = (const float*)d_in[9];
    const float* bm   = (const float*)d_in[10];
    const float* Wmo  = (const float*)d_in[11];
    const float* bmo  = (const float*)d_in[12];
    const float* Wa   = (const float*)d_in[13];
    const float* ba   = (const float*)d_in[14];
    const float* Wao  = (const float*)d_in[15];
    const float* bao  = (const float*)d_in[16];
    const float* Wef  = (const float*)d_in[17];
    const float* bef  = (const float*)d_in[18];
    const float* Wer  = (const float*)d_in[19];
    const float* ber  = (const float*)d_in[20];
    const float* Weo  = (const float*)d_in[21];
    const float* beo  = (const float*)d_in[22];
    const float* lw   = (const float*)d_in[23];
    float* out = (float*)d_out;
    float* wsf = (float*)d_ws;

    k_base<<<1, 256, 0, stream>>>(Xm, bfv, Wbf, bbf, Wbr, bbr, Wbo, bbo,
                                  Wm, bm, Wmo, bmo, lw, out, wsf);
    k_big<<<A_N + 1, 256, 0, stream>>>(X, Xm, Wa, ba, Wao, bao, Wef, lw, out, wsf);
    k_red<<<64, 256, 0, stream>>>(wsf);
    k_end<<<1, 256, 0, stream>>>(bef, Wer, ber, Weo, beo, lw, out, wsf);
}

// Round 2
// 117.819 us; speedup vs baseline: 1.6570x; 1.6570x over previous
//
#include <hip/hip_runtime.h>
#include <math.h>

#define A_N 2048
#define NLAYERS 2057

// ws layout (float offsets). part[0]=middle chunk, part[1+e]=expert e.
#define PART_OFF  0               // 2049*256 = 524544
#define PART2_OFF 524544          // 64*256 = 16384
#define GSUM_OFF  540928
#define WSUM_OFF  540929

// ---- helpers (256-thread sections) ----

// softmax-2 head: dest[0..1] = softmax(sx @ W2 + b2) * scale   (256 threads)
__device__ __forceinline__ void head256(const float* sx, float* r0, float* r1,
                                        const float* W2, const float* b2,
                                        float scale, float* dest, int t)
{
    float xv = sx[t];
    r0[t] = xv * W2[2*t];
    r1[t] = xv * W2[2*t+1];
    __syncthreads();
    for (int s = 128; s > 0; s >>= 1) {
        if (t < s) { r0[t] += r0[t+s]; r1[t] += r1[t+s]; }
        __syncthreads();
    }
    if (t == 0) {
        float o0 = r0[0] + b2[0], o1 = r1[0] + b2[1];
        float m  = fmaxf(o0, o1);
        float e0 = expf(o0 - m), e1 = expf(o1 - m);
        float inv = scale / (e0 + e1);
        dest[0] = e0 * inv;
        dest[1] = e1 * inv;
    }
    __syncthreads();
}

// sx = relu(sx @ W + b), W is [256][256] row-major (256 threads)
__device__ __forceinline__ void mv256(float* sx, const float* __restrict__ W,
                                      const float* __restrict__ b, int t)
{
    float acc = 0.f;
    #pragma unroll 16
    for (int k = 0; k < 256; ++k) acc += sx[k] * W[k*256 + t];
    acc = fmaxf(acc + b[t], 0.f);
    __syncthreads();
    sx[t] = acc;
    __syncthreads();
}

// ---- kernel 1: everything except end stack (2049 blocks x 256) ----
// block 0: mask sums + base stack + middle + middle chunk of We_first matvec
// block 1+e: aux expert e (+ its chunk), early-exit when masked
__global__ __launch_bounds__(256) void k_main(
    const float* __restrict__ X, const int* __restrict__ Xm,
    const float* __restrict__ bfv,
    const float* __restrict__ Wbf, const float* __restrict__ bbf,
    const float* __restrict__ Wbr, const float* __restrict__ bbr,
    const float* __restrict__ Wbo, const float* __restrict__ bbo,
    const float* __restrict__ Wm, const float* __restrict__ bm,
    const float* __restrict__ Wmo, const float* __restrict__ bmo,
    const float* __restrict__ Wa, const float* __restrict__ ba,
    const float* __restrict__ Wao, const float* __restrict__ bao,
    const float* __restrict__ Wef, const float* __restrict__ lw,
    float* __restrict__ out, float* __restrict__ ws)
{
    __shared__ float sg[256];        // the vector that feeds the We_first chunk
    __shared__ float sacc[4][256];   // scratch / reductions
    int b = blockIdx.x, t = threadIdx.x;
    float* part = ws + PART_OFF;

    if (b == 0) {
        // ---- mask-weighted sums ----
        float ga = 0.f;
        for (int a = t; a < A_N; a += 256) if (Xm[a] != 0) ga += lw[4 + a];
        sacc[0][t] = ga; __syncthreads();
        for (int s = 128; s > 0; s >>= 1) { if (t < s) sacc[0][t] += sacc[0][t+s]; __syncthreads(); }
        if (t == 0) {
            float gaux = sacc[0][0];
            ws[GSUM_OFF] = gaux + lw[2056];
            ws[WSUM_OFF] = lw[0]+lw[1]+lw[2]+lw[3] + gaux
                         + lw[2052]+lw[2053]+lw[2054]+lw[2055]+lw[2056];
        }
        __syncthreads();

        // ---- base stack ----
        sg[t] = fmaxf(bfv[0] * Wbf[t] + bbf[t], 0.f);
        __syncthreads();
        head256(sg, sacc[0], sacc[1], Wbo, bbo, lw[0], out + 2, t);
        for (int i = 0; i < 3; ++i) {
            mv256(sg, Wbr + i*65536, bbr + i*256, t);
            head256(sg, sacc[0], sacc[1], Wbo + (i+1)*512, bbo + (i+1)*2,
                    lw[i+1], out + 2 + (i+1)*2, t);
        }
        // ---- middle ----
        mv256(sg, Wm, bm, t);
        head256(sg, sacc[0], sacc[1], Wmo, bmo, lw[2056], out + 2 + 2056*2, t);
        sg[t] *= lw[2056];           // middle * lw (gsum divide deferred)
        __syncthreads();
    } else {
        int e = b - 1;
        if (Xm[e] == 0) {            // masked expert: skip 256KB chunk entirely
            if (t == 0) { out[2 + (4+e)*2] = 0.f; out[2 + (4+e)*2 + 1] = 0.f; }
            return;                  // k_red skips this part row via Xm
        }
        float xv = X[e];
        float w  = lw[4 + e];
        float h  = fmaxf(xv * Wa[e*256 + t] + ba[e*256 + t], 0.f);
        float2 wo = *(const float2*)&Wao[(size_t)e*512 + 2*t];
        sacc[0][t] = h * wo.x;
        sacc[1][t] = h * wo.y;
        sg[t] = h * w;               // u = h*mask*lw (mask==1 here)
        __syncthreads();
        for (int s = 128; s > 0; s >>= 1) {
            if (t < s) { sacc[0][t] += sacc[0][t+s]; sacc[1][t] += sacc[1][t+s]; }
            __syncthreads();
        }
        if (t == 0) {
            float o0 = sacc[0][0] + bao[2*e], o1 = sacc[1][0] + bao[2*e+1];
            float m  = fmaxf(o0, o1);
            float e0 = expf(o0 - m), e1 = expf(o1 - m);
            float inv = w / (e0 + e1);   // * lw * mask; /wsum deferred
            out[2 + (4+e)*2]     = e0 * inv;
            out[2 + (4+e)*2 + 1] = e1 * inv;
        }
        __syncthreads();
    }

    // ---- partial matvec: 256 rows of We_first for this chunk ----
    // chunk row base: block 0 -> rows [A*256, A*256+256) (middle), expert e -> [e*256, ...)
    size_t rowbase = (b == 0) ? (size_t)A_N * 65536 : (size_t)(b - 1) * 65536;
    int quad = t >> 6, lane = t & 63;
    const float4* Wrow = (const float4*)(Wef + rowbase);
    float4 acc = {0.f, 0.f, 0.f, 0.f};
    #pragma unroll 4
    for (int it = 0; it < 64; ++it) {
        int r = it*4 + quad;
        float gv = sg[r];
        float4 wv = Wrow[(size_t)r*64 + lane];
        acc.x += gv*wv.x; acc.y += gv*wv.y; acc.z += gv*wv.z; acc.w += gv*wv.w;
    }
    sacc[quad][lane*4 + 0] = acc.x;
    sacc[quad][lane*4 + 1] = acc.y;
    sacc[quad][lane*4 + 2] = acc.z;
    sacc[quad][lane*4 + 3] = acc.w;
    __syncthreads();
    part[b*256 + t] = sacc[0][t] + sacc[1][t] + sacc[2][t] + sacc[3][t];
}

// ---- kernel 2: reduce part[2049][256] -> part2[64][256], skipping masked ----
__global__ __launch_bounds__(256) void k_red(const int* __restrict__ Xm,
                                             float* __restrict__ ws)
{
    int r = blockIdx.x, t = threadIdx.x;
    float acc = 0.f;
    for (int b = r; b < A_N + 1; b += 64) {
        if (b == 0 || Xm[b-1] != 0) acc += ws[PART_OFF + b*256 + t];
    }
    ws[PART2_OFF + r*256 + t] = acc;
}

// ---- kernel 3: end stack + final combine (1 block x 1024) ----
__global__ __launch_bounds__(1024) void k_end(
    const float* __restrict__ bef, const float* __restrict__ Wer,
    const float* __restrict__ ber, const float* __restrict__ Weo,
    const float* __restrict__ beo, const float* __restrict__ lw,
    float* __restrict__ out, float* __restrict__ ws)
{
    __shared__ float sx[256];
    __shared__ float racc[4][256];
    __shared__ float red0[1024], red1[1024];
    __shared__ float endraw[4][2];
    int tid = threadIdx.x;
    int q = tid >> 8, t = tid & 255;

    // finish reduce: part2[64][256] -> acc[256], /gsum, bias, relu
    float acc = 0.f;
    #pragma unroll
    for (int j = 0; j < 16; ++j) acc += ws[PART2_OFF + (q*16 + j)*256 + t];
    racc[q][t] = acc;
    __syncthreads();
    float gsum = ws[GSUM_OFF];
    if (tid < 256) {
        float v = racc[0][t] + racc[1][t] + racc[2][t] + racc[3][t];
        sx[t] = fmaxf(v / gsum + bef[t], 0.f);
    }
    __syncthreads();

    // head on 256-guard (others pass through syncs)
    #define HEAD_G(W2, B2, SCALE, DEST)                                         \
    {                                                                           \
        if (tid < 256) { red0[tid] = sx[tid]*(W2)[2*tid]; red1[tid] = sx[tid]*(W2)[2*tid+1]; } \
        __syncthreads();                                                        \
        for (int s = 128; s > 0; s >>= 1) {                                     \
            if (tid < s) { red0[tid] += red0[tid+s]; red1[tid] += red1[tid+s]; }\
            __syncthreads();                                                    \
        }                                                                       \
        if (tid == 0) {                                                         \
            float o0 = red0[0] + (B2)[0], o1 = red1[0] + (B2)[1];               \
            float m  = fmaxf(o0, o1);                                           \
            float e0 = expf(o0 - m), e1 = expf(o1 - m);                         \
            float inv = (SCALE) / (e0 + e1);                                    \
            (DEST)[0] = e0 * inv; (DEST)[1] = e1 * inv;                         \
        }                                                                       \
        __syncthreads();                                                        \
    }

    HEAD_G(Weo, beo, lw[2052], &endraw[0][0]);
    for (int i = 0; i < 3; ++i) {
        // mv1024: K-split 4-way
        const float* W = Wer + i*65536;
        float a2 = 0.f;
        const float* Wq = W + (q*64)*256;
        #pragma unroll 8
        for (int k = 0; k < 64; ++k) a2 += sx[q*64 + k] * Wq[k*256 + t];
        racc[q][t] = a2;
        __syncthreads();
        if (tid < 256) {
            float v = racc[0][t] + racc[1][t] + racc[2][t] + racc[3][t];
            sx[t] = fmaxf(v + ber[i*256 + t], 0.f);
        }
        __syncthreads();
        HEAD_G(Weo + (i+1)*512, beo + (i+1)*2, lw[2053 + i], &endraw[i+1][0]);
    }

    // rescale all rows by 1/wsum, accumulate final logit
    float invw = 1.f / ws[WSUM_OFF];
    float s0 = 0.f, s1 = 0.f;
    for (int i = tid; i < NLAYERS; i += 1024) {
        float v0, v1;
        if (i >= 2052 && i < 2056) { v0 = endraw[i-2052][0]; v1 = endraw[i-2052][1]; }
        else                        { v0 = out[2 + 2*i];      v1 = out[2 + 2*i + 1]; }
        v0 *= invw; v1 *= invw;
        out[2 + 2*i]     = v0;
        out[2 + 2*i + 1] = v1;
        s0 += v0; s1 += v1;
    }
    red0[tid] = s0; red1[tid] = s1; __syncthreads();
    for (int s = 512; s > 0; s >>= 1) {
        if (tid < s) { red0[tid] += red0[tid+s]; red1[tid] += red1[tid+s]; }
        __syncthreads();
    }
    if (tid == 0) { out[0] = red0[0]; out[1] = red1[0]; }
}

extern "C" void kernel_launch(void* const* d_in, const int* in_sizes, int n_in,
                              void* d_out, int out_size, void* d_ws, size_t ws_size,
                              hipStream_t stream)
{
    const float* X    = (const float*)d_in[0];
    const int*   Xm   = (const int*)  d_in[1];
    const float* bfv  = (const float*)d_in[2];
    const float* Wbf  = (const float*)d_in[3];
    const float* bbf  = (const float*)d_in[4];
    const float* Wbr  = (const float*)d_in[5];
    const float* bbr  = (const float*)d_in[6];
    const float* Wbo  = (const float*)d_in[7];
    const float* bbo  = (const float*)d_in[8];
    const float* Wm   = (const float*)d_in[9];
    const float* bm   = (const float*)d_in[10];
    const float* Wmo  = (const float*)d_in[11];
    const float* bmo  = (const float*)d_in[12];
    const float* Wa   = (const float*)d_in[13];
    const float* ba   = (const float*)d_in[14];
    const float* Wao  = (const float*)d_in[15];
    const float* bao  = (const float*)d_in[16];
    const float* Wef  = (const float*)d_in[17];
    const float* bef  = (const float*)d_in[18];
    const float* Wer  = (const float*)d_in[19];
    const float* ber  = (const float*)d_in[20];
    const float* Weo  = (const float*)d_in[21];
    const float* beo  = (const float*)d_in[22];
    const float* lw   = (const float*)d_in[23];
    float* out = (float*)d_out;
    float* wsf = (float*)d_ws;

    k_main<<<A_N + 1, 256, 0, stream>>>(X, Xm, bfv, Wbf, bbf, Wbr, bbr, Wbo, bbo,
                                        Wm, bm, Wmo, bmo, Wa, ba, Wao, bao,
                                        Wef, lw, out, wsf);
    k_red<<<64, 256, 0, stream>>>(Xm, wsf);
    k_end<<<1, 1024, 0, stream>>>(bef, Wer, ber, Weo, beo, lw, out, wsf);
}